// Round 11
// baseline (3909.444 us; speedup 1.0000x reference)
//
#include <hip/hip_runtime.h>

#define TT 2048
#define BB 128
#define DD 128
#define HH 256

typedef float f32x4 __attribute__((ext_vector_type(4)));
typedef _Float16 f16x8 __attribute__((ext_vector_type(8)));
typedef _Float16 f16x4 __attribute__((ext_vector_type(4)));

static __device__ __forceinline__ float fast_tanh(float s) {
    float e = __expf(2.0f * s);
    float r = __builtin_amdgcn_rcpf(e + 1.0f);
    return __builtin_fmaf(-2.0f, r, 1.0f);
}

static __device__ __forceinline__ void lds_barrier() {
    __builtin_amdgcn_sched_barrier(0);
    asm volatile("s_waitcnt lgkmcnt(0)" ::: "memory");
    __builtin_amdgcn_s_barrier();
    __builtin_amdgcn_sched_barrier(0);
}

// ---------------------------------------------------------------------------
// xproj (unchanged, ~97 us)
// ---------------------------------------------------------------------------
__global__ __launch_bounds__(256, 2) void xproj_mfma(
    const float* __restrict__ x, const float* __restrict__ W_in,
    const float* __restrict__ b_in, const float* __restrict__ b_h,
    float* __restrict__ out)
{
    __shared__ short xs[64 * 128];
    const int tid  = threadIdx.x;
    const int lane = tid & 63;
    const int w    = tid >> 6;
    const int lrow = lane & 15;
    const int lgrp = lane >> 4;
    const long rbase = (long)blockIdx.x * 64;

    f16x8 bw[4][4];
    #pragma unroll
    for (int kc = 0; kc < 4; ++kc)
        #pragma unroll
        for (int nt = 0; nt < 4; ++nt) {
            const int n = w * 64 + nt * 16 + lrow;
            #pragma unroll
            for (int i = 0; i < 8; ++i)
                bw[kc][nt][i] = (_Float16)W_in[(kc * 32 + lgrp * 8 + i) * HH + n];
        }
    float bias[4];
    #pragma unroll
    for (int nt = 0; nt < 4; ++nt) {
        const int n = w * 64 + nt * 16 + lrow;
        bias[nt] = b_in[n] + b_h[n];
    }
    {
        const float4* xg = (const float4*)(x + rbase * DD);
        #pragma unroll
        for (int th = 0; th < 8; ++th) {
            int idx = tid + th * 256;
            int r   = idx >> 5;
            int c4  = idx & 31;
            float4 v = xg[idx];
            f16x4 p;
            p[0] = (_Float16)v.x; p[1] = (_Float16)v.y;
            p[2] = (_Float16)v.z; p[3] = (_Float16)v.w;
            unsigned off = (unsigned)(r * 256 + c4 * 8);
            off ^= (unsigned)((r & 7) << 4);
            *(f16x4*)((char*)xs + off) = p;
        }
    }
    __syncthreads();

    #pragma unroll
    for (int mt = 0; mt < 4; ++mt) {
        const int r = mt * 16 + lrow;
        f16x8 a[4];
        #pragma unroll
        for (int kc = 0; kc < 4; ++kc) {
            unsigned off = (unsigned)(r * 256 + kc * 64 + lgrp * 16);
            off ^= (unsigned)((r & 7) << 4);
            a[kc] = *(const f16x8*)((const char*)xs + off);
        }
        f32x4 acc[4];
        #pragma unroll
        for (int nt = 0; nt < 4; ++nt) { f32x4 c = {bias[nt], bias[nt], bias[nt], bias[nt]}; acc[nt] = c; }
        #pragma unroll
        for (int kc = 0; kc < 4; ++kc)
            #pragma unroll
            for (int nt = 0; nt < 4; ++nt)
                acc[nt] = __builtin_amdgcn_mfma_f32_16x16x32_f16(a[kc], bw[kc][nt], acc[nt], 0, 0, 0);
        #pragma unroll
        for (int nt = 0; nt < 4; ++nt)
            #pragma unroll
            for (int rr = 0; rr < 4; ++rr)
                out[(rbase + mt * 16 + lgrp * 4 + rr) * HH + w * 64 + nt * 16 + lrow] = acc[nt][rr];
    }
}

// ---------------------------------------------------------------------------
// ABLATION step. V=0 real, V=1 full->ws, V=2 no global I/O, V=3 no tanh,
// V=4 no s_barrier. All share the r9 structure (8 WGs, 4 waves, 16 rows).
// ---------------------------------------------------------------------------
template<int V, bool PF>
static __device__ __forceinline__ void rec_step_v(
    const float* pld, float* pst,
    f32x4 (&xp)[4],
    const short* curb, short* nxtb,
    const f16x8 (&wh)[4][8], int lrow, int lgrp, int jb)
{
    f16x8 bbf[8];
    #pragma unroll
    for (int kc = 0; kc < 8; ++kc) {
        unsigned off = (unsigned)(lrow * 512 + kc * 64 + lgrp * 16);
        off ^= (unsigned)((lrow & 7) << 4);
        bbf[kc] = *(const f16x8*)((const char*)curb + off);
    }

    f32x4 acc[4];
    #pragma unroll
    for (int mt = 0; mt < 4; ++mt) acc[mt] = xp[mt];

    if constexpr (V != 2) {
        if (PF) {
            #pragma unroll
            for (int mt = 0; mt < 4; ++mt)
                xp[mt] = *(const f32x4*)(pld + mt * 16);
        }
    }

    #pragma unroll
    for (int kc = 0; kc < 8; ++kc)
        #pragma unroll
        for (int mt = 0; mt < 4; ++mt)
            acc[mt] = __builtin_amdgcn_mfma_f32_16x16x32_f16(wh[mt][kc], bbf[kc], acc[mt], 0, 0, 0);

    #pragma unroll
    for (int mt = 0; mt < 4; ++mt) {
        f32x4 hv;
        if constexpr (V == 3) {
            #pragma unroll
            for (int rr = 0; rr < 4; ++rr) hv[rr] = acc[mt][rr] * 0.0625f;
        } else {
            #pragma unroll
            for (int rr = 0; rr < 4; ++rr) hv[rr] = fast_tanh(acc[mt][rr]);
        }
        if constexpr (V != 2) {
            *(f32x4*)(pst + mt * 16) = hv;
        } else {
            xp[mt] = hv;   // register feedback: keeps chain live, values bounded
        }
        f16x4 q;
        #pragma unroll
        for (int rr = 0; rr < 4; ++rr) q[rr] = (_Float16)hv[rr];
        unsigned off = (unsigned)(lrow * 512 + (jb + mt * 16 + lgrp * 4) * 2);
        off ^= (unsigned)((lrow & 7) << 4);
        *(f16x4*)((char*)nxtb + off) = q;
    }
    if constexpr (V == 4) {
        __builtin_amdgcn_sched_barrier(0);
        asm volatile("s_waitcnt lgkmcnt(0)" ::: "memory");
        __builtin_amdgcn_sched_barrier(0);
    } else {
        lds_barrier();
    }
}

// common prologue packaged: weights, LDS h0, base offsets
struct RecSetup {
    int lrow, lgrp, jb, b0;
    long base;   // element offset within a [BB][HH] plane for this thread
};

static __device__ __forceinline__ RecSetup rec_prologue(
    const float* h0, const float* W_h, f16x8 (&wh)[4][8], short* hb0)
{
    const int tid  = threadIdx.x;
    const int lane = tid & 63;
    const int w    = tid >> 6;
    RecSetup s;
    s.lrow = lane & 15;
    s.lgrp = lane >> 4;
    s.b0   = blockIdx.x * 16;
    s.jb   = w * 64;
    #pragma unroll
    for (int mt = 0; mt < 4; ++mt) {
        const int j = s.jb + mt * 16 + s.lrow;
        #pragma unroll
        for (int kc = 0; kc < 8; ++kc)
            #pragma unroll
            for (int i = 0; i < 8; ++i)
                wh[mt][kc][i] = (_Float16)W_h[(kc * 32 + s.lgrp * 8 + i) * HH + j];
    }
    {
        const int g  = tid >> 4;
        const int k0 = (tid & 15) * 16;
        const float* hp = h0 + (s.b0 + g) * HH + k0;
        #pragma unroll
        for (int cc = 0; cc < 2; ++cc) {
            f16x8 p;
            #pragma unroll
            for (int i = 0; i < 8; ++i) p[i] = (_Float16)hp[cc * 8 + i];
            unsigned off = (unsigned)(g * 512 + k0 * 2 + cc * 16);
            off ^= (unsigned)((g & 7) << 4);
            *(f16x8*)((char*)hb0 + off) = p;
        }
    }
    s.base = (long)(s.b0 + s.lrow) * HH + s.jb + s.lgrp * 4;
    return s;
}

// ------------------------- REAL kernel (V0, r9) ----------------------------
__global__ __launch_bounds__(256, 1) void rnn_rec_mfma(
    const float* __restrict__ h0, const float* __restrict__ W_h, float* io)
{
    __shared__ short hb0[16 * 256];
    __shared__ short hb1[16 * 256];
    f16x8 wh[4][8];
    RecSetup s = rec_prologue(h0, W_h, wh, hb0);

    const long S = (long)BB * HH;
    const float* pld = io + s.base + 2 * S;
    float*       pst = io + s.base;

    f32x4 xa[4], xb[4];
    #pragma unroll
    for (int mt = 0; mt < 4; ++mt) {
        xa[mt] = *(const f32x4*)(io + s.base + 0 * S + mt * 16);
        xb[mt] = *(const f32x4*)(io + s.base + 1 * S + mt * 16);
    }
    __syncthreads();

    for (int t = 0; t < TT - 2; t += 2) {
        rec_step_v<0, true>(pld, pst, xa, hb0, hb1, wh, s.lrow, s.lgrp, s.jb);
        pld += S; pst += S;
        rec_step_v<0, true>(pld, pst, xb, hb1, hb0, wh, s.lrow, s.lgrp, s.jb);
        pld += S; pst += S;
    }
    rec_step_v<0, false>(pld, pst, xa, hb0, hb1, wh, s.lrow, s.lgrp, s.jb);
    pst += S;
    rec_step_v<0, false>(pld, pst, xb, hb1, hb0, wh, s.lrow, s.lgrp, s.jb);
}

// ------------------------- ablation variants -------------------------------
// STEPS=512; reads real xproj from xpsrc (d_out, untouched yet); stores to a
// 16-plane (2 MB) window in ws.
template<int V>
__global__ __launch_bounds__(256, 1) void rec_var(
    const float* __restrict__ h0, const float* __restrict__ W_h,
    const float* __restrict__ xpsrc, float* __restrict__ ws)
{
    __shared__ short hb0[16 * 256];
    __shared__ short hb1[16 * 256];
    f16x8 wh[4][8];
    RecSetup s = rec_prologue(h0, W_h, wh, hb0);

    const long S = (long)BB * HH;
    f32x4 xa[4], xb[4];
    #pragma unroll
    for (int mt = 0; mt < 4; ++mt) {
        xa[mt] = *(const f32x4*)(xpsrc + s.base + 0 * S + mt * 16);
        xb[mt] = *(const f32x4*)(xpsrc + s.base + 1 * S + mt * 16);
    }
    __syncthreads();

    const int STEPS = 512;
    for (int t = 0; t < STEPS; t += 2) {
        {
            const float* pld = xpsrc + s.base + (long)(t + 2) * S;
            float*       pst = ws + s.base + (long)(t & 15) * S;
            rec_step_v<V, true>(pld, pst, xa, hb0, hb1, wh, s.lrow, s.lgrp, s.jb);
        }
        {
            const float* pld = xpsrc + s.base + (long)(t + 3) * S;
            float*       pst = ws + s.base + (long)((t + 1) & 15) * S;
            rec_step_v<V, true>(pld, pst, xb, hb1, hb0, wh, s.lrow, s.lgrp, s.jb);
        }
    }
    // keep-alive (esp. V2): final state -> ws plane 0
    #pragma unroll
    for (int mt = 0; mt < 4; ++mt) {
        *(f32x4*)(ws + s.base + mt * 16) = xa[mt];
        *(f32x4*)(ws + s.base + mt * 16 + 64) = xb[mt];
    }
}

extern "C" void kernel_launch(void* const* d_in, const int* in_sizes, int n_in,
                              void* d_out, int out_size, void* d_ws, size_t ws_size,
                              hipStream_t stream) {
    const float* x    = (const float*)d_in[0];
    const float* h0   = (const float*)d_in[1];
    const float* W_in = (const float*)d_in[2];
    const float* b_in = (const float*)d_in[3];
    const float* W_h  = (const float*)d_in[4];
    const float* b_h  = (const float*)d_in[5];
    float* out = (float*)d_out;
    float* ws  = (float*)d_ws;

    // Phase 1: xproj -> d_out
    xproj_mfma<<<(TT * BB) / 64, 256, 0, stream>>>(x, W_in, b_in, b_h, out);

    // Ablation probes (read d_out xproj, write d_ws window; skipped if ws too small)
    if (ws_size >= (size_t)16 * BB * HH * 4) {
        rec_var<1><<<BB / 16, 256, 0, stream>>>(h0, W_h, out, ws);  // full, stores->ws
        rec_var<2><<<BB / 16, 256, 0, stream>>>(h0, W_h, out, ws);  // no global I/O
        rec_var<3><<<BB / 16, 256, 0, stream>>>(h0, W_h, out, ws);  // no tanh
        rec_var<4><<<BB / 16, 256, 0, stream>>>(h0, W_h, out, ws);  // no s_barrier
    }

    // Phase 2: real recurrence (overwrites d_out with h)
    rnn_rec_mfma<<<BB / 16, 256, 0, stream>>>(h0, W_h, out);
}

// Round 12
// 2152.636 us; speedup vs baseline: 1.8161x; 1.8161x over previous
//
#include <hip/hip_runtime.h>

#define TT 2048
#define BB 128
#define DD 128
#define HH 256

typedef float f32x4 __attribute__((ext_vector_type(4)));
typedef _Float16 f16x8 __attribute__((ext_vector_type(8)));
typedef _Float16 f16x4 __attribute__((ext_vector_type(4)));

static __device__ __forceinline__ float fast_tanh(float s) {
    // tanh(s) = 1 - 2/(exp(2s)+1); exp->inf and ->0 both saturate correctly
    float e = __expf(2.0f * s);
    float r = __builtin_amdgcn_rcpf(e + 1.0f);
    return __builtin_fmaf(-2.0f, r, 1.0f);
}

// LDS-only barrier: drain lgkmcnt but NOT vmcnt (global h-stores / xp-loads
// stay in flight across the barrier). sched_barrier(0) fences per rule #18.
static __device__ __forceinline__ void lds_barrier() {
    __builtin_amdgcn_sched_barrier(0);
    asm volatile("s_waitcnt lgkmcnt(0)" ::: "memory");
    __builtin_amdgcn_s_barrier();
    __builtin_amdgcn_sched_barrier(0);
}

// ---------------------------------------------------------------------------
// xproj (unchanged, ~97 us)
// ---------------------------------------------------------------------------
__global__ __launch_bounds__(256, 2) void xproj_mfma(
    const float* __restrict__ x, const float* __restrict__ W_in,
    const float* __restrict__ b_in, const float* __restrict__ b_h,
    float* __restrict__ out)
{
    __shared__ short xs[64 * 128];
    const int tid  = threadIdx.x;
    const int lane = tid & 63;
    const int w    = tid >> 6;
    const int lrow = lane & 15;
    const int lgrp = lane >> 4;
    const long rbase = (long)blockIdx.x * 64;

    f16x8 bw[4][4];
    #pragma unroll
    for (int kc = 0; kc < 4; ++kc)
        #pragma unroll
        for (int nt = 0; nt < 4; ++nt) {
            const int n = w * 64 + nt * 16 + lrow;
            #pragma unroll
            for (int i = 0; i < 8; ++i)
                bw[kc][nt][i] = (_Float16)W_in[(kc * 32 + lgrp * 8 + i) * HH + n];
        }
    float bias[4];
    #pragma unroll
    for (int nt = 0; nt < 4; ++nt) {
        const int n = w * 64 + nt * 16 + lrow;
        bias[nt] = b_in[n] + b_h[n];
    }
    {
        const float4* xg = (const float4*)(x + rbase * DD);
        #pragma unroll
        for (int th = 0; th < 8; ++th) {
            int idx = tid + th * 256;
            int r   = idx >> 5;
            int c4  = idx & 31;
            float4 v = xg[idx];
            f16x4 p;
            p[0] = (_Float16)v.x; p[1] = (_Float16)v.y;
            p[2] = (_Float16)v.z; p[3] = (_Float16)v.w;
            unsigned off = (unsigned)(r * 256 + c4 * 8);
            off ^= (unsigned)((r & 7) << 4);
            *(f16x4*)((char*)xs + off) = p;
        }
    }
    __syncthreads();

    #pragma unroll
    for (int mt = 0; mt < 4; ++mt) {
        const int r = mt * 16 + lrow;
        f16x8 a[4];
        #pragma unroll
        for (int kc = 0; kc < 4; ++kc) {
            unsigned off = (unsigned)(r * 256 + kc * 64 + lgrp * 16);
            off ^= (unsigned)((r & 7) << 4);
            a[kc] = *(const f16x8*)((const char*)xs + off);
        }
        f32x4 acc[4];
        #pragma unroll
        for (int nt = 0; nt < 4; ++nt) { f32x4 c = {bias[nt], bias[nt], bias[nt], bias[nt]}; acc[nt] = c; }
        #pragma unroll
        for (int kc = 0; kc < 4; ++kc)
            #pragma unroll
            for (int nt = 0; nt < 4; ++nt)
                acc[nt] = __builtin_amdgcn_mfma_f32_16x16x32_f16(a[kc], bw[kc][nt], acc[nt], 0, 0, 0);
        #pragma unroll
        for (int nt = 0; nt < 4; ++nt)
            #pragma unroll
            for (int rr = 0; rr < 4; ++rr)
                out[(rbase + mt * 16 + lgrp * 4 + rr) * HH + w * 64 + nt * 16 + lrow] = acc[nt][rr];
    }
}

// ---------------------------------------------------------------------------
// Recurrence, PHASE-FUSED: 8 WGs x 16 batch rows; 256 threads = 4 waves
// (1/SIMD); wave w owns h-cols [w*64,+64).  D[j][g] = sum_k W_h[k][j] h[g][k].
// r11 diagnosis: per step MFMA-busy ~508 + VALU ~830 + LDS/waits ~900 execute
// SERIALLY (kc-interleaved chains -> all tanh depends on the MFMA tail ->
// scheduler has no legal overlap). Fix: chains SEQUENTIAL per mt with tanh/
// global-store/LDS-write fused right after each chain, so tanh(mt) VALU can
// be scheduled into chains(mt+1..3)'s MFMA pipe gaps; xp prefetch + h stores
// are extra filler inside the MFMA regions.
// ---------------------------------------------------------------------------
template<bool PF>
static __device__ __forceinline__ void rec_step(
    const float* pld, float* pst,
    f32x4 (&xp)[4],                  // in: C-init for this step; out (PF): t+2
    const short* curb, short* nxtb,
    const f16x8 (&wh)[4][8], int lrow, int lgrp, int jb)
{
    // B-frags: h[g = lane&15][k = kc*32 + lgrp*8 + i] from swizzled LDS
    f16x8 bbf[8];
    #pragma unroll
    for (int kc = 0; kc < 8; ++kc) {
        unsigned off = (unsigned)(lrow * 512 + kc * 64 + lgrp * 16);
        off ^= (unsigned)((lrow & 7) << 4);
        bbf[kc] = *(const f16x8*)((const char*)curb + off);
    }

    // chain-sequential with fused epilogue per mt
    #pragma unroll
    for (int mt = 0; mt < 4; ++mt) {
        f32x4 acc = xp[mt];
        if (PF)   // anti-dep on xp[mt]: issues early, consumed 2 steps later
            xp[mt] = *(const f32x4*)(pld + mt * 16);
        #pragma unroll
        for (int kc = 0; kc < 8; ++kc)
            acc = __builtin_amdgcn_mfma_f32_16x16x32_f16(wh[mt][kc], bbf[kc], acc, 0, 0, 0);

        f32x4 hv;
        #pragma unroll
        for (int rr = 0; rr < 4; ++rr) hv[rr] = fast_tanh(acc[rr]);
        *(f32x4*)(pst + mt * 16) = hv;           // global h store (fire & forget)
        f16x4 q;
        #pragma unroll
        for (int rr = 0; rr < 4; ++rr) q[rr] = (_Float16)hv[rr];
        // D mapping: col g = lane&15 (batch row), row j = jb + mt*16 + lgrp*4 + rr
        unsigned off = (unsigned)(lrow * 512 + (jb + mt * 16 + lgrp * 4) * 2);
        off ^= (unsigned)((lrow & 7) << 4);
        *(f16x4*)((char*)nxtb + off) = q;
    }
    lds_barrier();
}

__global__ __launch_bounds__(256, 1) void rnn_rec_mfma(
    const float* __restrict__ h0, const float* __restrict__ W_h, float* io)
{
    __shared__ short hb0[16 * 256];  // f16 swizzled h, buffer 0 (8 KB)
    __shared__ short hb1[16 * 256];  // buffer 1
    const int tid  = threadIdx.x;
    const int lane = tid & 63;
    const int w    = tid >> 6;       // 0..3
    const int lrow = lane & 15;
    const int lgrp = lane >> 4;
    const int b0   = blockIdx.x * 16;
    const int jb   = w * 64;

    // A-frags: A[j][k] = W_h[k][j], j = jb + mt*16 + lrow, k = kc*32 + lgrp*8 + i
    f16x8 wh[4][8];
    #pragma unroll
    for (int mt = 0; mt < 4; ++mt) {
        const int j = jb + mt * 16 + lrow;
        #pragma unroll
        for (int kc = 0; kc < 8; ++kc)
            #pragma unroll
            for (int i = 0; i < 8; ++i)
                wh[mt][kc][i] = (_Float16)W_h[(kc * 32 + lgrp * 8 + i) * HH + j];
    }

    // h_lds[0] <- h0 (fp32 -> f16, swizzled [g][k])
    {
        const int g  = tid >> 4;            // 0..15
        const int k0 = (tid & 15) * 16;     // 16 f16 per thread
        const float* hp = h0 + (b0 + g) * HH + k0;
        #pragma unroll
        for (int cc = 0; cc < 2; ++cc) {
            f16x8 p;
            #pragma unroll
            for (int i = 0; i < 8; ++i) p[i] = (_Float16)hp[cc * 8 + i];
            unsigned off = (unsigned)(g * 512 + k0 * 2 + cc * 16);
            off ^= (unsigned)((g & 7) << 4);
            *(f16x8*)((char*)hb0 + off) = p;
        }
    }

    // running pointers (strength-reduced)
    const long S = (long)BB * HH;
    const long base = (long)(b0 + lrow) * HH + jb + lgrp * 4;
    const float* pld = io + base + 2 * S;     // prefetch t+2
    float*       pst = io + base;             // store t

    // xp preload (C-init) for t=0 / t=1 (distance-2 parity registers)
    f32x4 xa[4], xb[4];
    #pragma unroll
    for (int mt = 0; mt < 4; ++mt) {
        xa[mt] = *(const f32x4*)(io + base + 0 * S + mt * 16);
        xb[mt] = *(const f32x4*)(io + base + 1 * S + mt * 16);
    }
    __syncthreads();

    for (int t = 0; t < TT - 2; t += 2) {
        rec_step<true>(pld, pst, xa, hb0, hb1, wh, lrow, lgrp, jb);
        pld += S; pst += S;
        rec_step<true>(pld, pst, xb, hb1, hb0, wh, lrow, lgrp, jb);
        pld += S; pst += S;
    }
    // peeled final two steps: no prefetch loads (no OOB, no alias clamp)
    rec_step<false>(pld, pst, xa, hb0, hb1, wh, lrow, lgrp, jb);
    pst += S;
    rec_step<false>(pld, pst, xb, hb1, hb0, wh, lrow, lgrp, jb);
}

extern "C" void kernel_launch(void* const* d_in, const int* in_sizes, int n_in,
                              void* d_out, int out_size, void* d_ws, size_t ws_size,
                              hipStream_t stream) {
    const float* x    = (const float*)d_in[0];
    const float* h0   = (const float*)d_in[1];
    const float* W_in = (const float*)d_in[2];
    const float* b_in = (const float*)d_in[3];
    const float* W_h  = (const float*)d_in[4];
    const float* b_h  = (const float*)d_in[5];
    float* out = (float*)d_out;

    xproj_mfma<<<(TT * BB) / 64, 256, 0, stream>>>(x, W_in, b_in, b_h, out);
    rnn_rec_mfma<<<BB / 16, 256, 0, stream>>>(h0, W_h, out);
}